// Round 10
// baseline (167.862 us; speedup 1.0000x reference)
//
#include <hip/hip_runtime.h>
#include <hip/hip_bf16.h>

// Problem constants (N=2, C=256, H=W=64) — float32 I/O per reference.
#define NBATCH 2
#define CCH    256
#define LLEN   4096      // H*W
#define NGROUP 8
#define CPG    32        // C / NGROUP
#define NHEAD  4
#define HD     64        // C / NHEAD
#define GEPS   1e-5f
#define KSPLIT 4         // grid-level key split; x4 waves = 16-way total
// q pre-scale: hd^-0.5 * log2(e); scores then feed v_exp_f32 (2^x) directly.
#define QSCALE 0.18033688011112042f
#define RS 264           // GEMM LDS row stride (ushorts)

typedef short bf16x8 __attribute__((ext_vector_type(8)));
typedef float f32x4  __attribute__((ext_vector_type(4)));

__device__ __forceinline__ unsigned short f2b(float f) {
  unsigned u = __float_as_uint(f);
  u += 0x7FFFu + ((u >> 16) & 1u);
  return (unsigned short)(u >> 16);
}
__device__ __forceinline__ unsigned pack2bf(float a, float b) {
  __hip_bfloat162 h = __float22bfloat162_rn(make_float2(a, b));
  union { __hip_bfloat162 h; unsigned u; } c;
  c.h = h;
  return c.u;
}
__device__ __forceinline__ float b2f(unsigned short h) {
  return __uint_as_float(((unsigned int)h) << 16);
}
__device__ __forceinline__ float exp2_(float x) {
#if __has_builtin(__builtin_amdgcn_exp2f)
  return __builtin_amdgcn_exp2f(x);
#else
  return exp2f(x);
#endif
}

// ------- setup: wcvt (blocks 0..255) | gn partial sums (256..383) | mask (384..415) -------
__global__ __launch_bounds__(256) void setup_kernel(
    const float* __restrict__ qw, const float* __restrict__ kw,
    const float* __restrict__ vw, const float* __restrict__ pw,
    const float* __restrict__ qb, const float* __restrict__ kb,
    const float* __restrict__ vb, const float* __restrict__ pb,
    const float* __restrict__ x, const int* __restrict__ mask,
    unsigned short* __restrict__ w16, float* __restrict__ bias_ws,
    float* __restrict__ part, float* __restrict__ out2) {
  __shared__ float rs[4], rss[4];
  const int b = blockIdx.x;
  const int t = threadIdx.x;
  if (b < 256) {
    const int idx = b * 256 + t;
    const int m = idx >> 14;
    const float* src[4] = {qw, kw, vw, pw};
    const float sc = (m == 0) ? QSCALE : 1.0f;
    const float4 v = ((const float4*)src[m])[idx & 16383];
    ushort4 o;
    o.x = f2b(v.x * sc); o.y = f2b(v.y * sc);
    o.z = f2b(v.z * sc); o.w = f2b(v.w * sc);
    ((ushort4*)w16)[idx] = o;
    if (b == 0) {
      bias_ws[t]       = qb[t] * QSCALE;
      bias_ws[256 + t] = kb[t];
      bias_ws[512 + t] = vb[t];
      bias_ws[768 + t] = pb[t];
    }
  } else if (b < 384) {
    const int sb = b - 256;
    const int gidx = sb >> 3, sub = sb & 7;
    const float4* xp = (const float4*)(x + (size_t)gidx * (CPG * LLEN)) + (size_t)sub * 4096;
    float s = 0.f, ss = 0.f;
    for (int i = t; i < 4096; i += 256) {
      const float4 v = xp[i];
      s += v.x + v.y + v.z + v.w;
      ss = fmaf(v.x, v.x, ss);
      ss = fmaf(v.y, v.y, ss);
      ss = fmaf(v.z, v.z, ss);
      ss = fmaf(v.w, v.w, ss);
    }
#pragma unroll
    for (int off = 32; off; off >>= 1) {
      s  += __shfl_down(s, off);
      ss += __shfl_down(ss, off);
    }
    if ((t & 63) == 0) { rs[t >> 6] = s; rss[t >> 6] = ss; }
    __syncthreads();
    if (t == 0) {
      part[sb * 2 + 0] = rs[0] + rs[1] + rs[2] + rs[3];
      part[sb * 2 + 1] = rss[0] + rss[1] + rss[2] + rss[3];
    }
  } else {
    const int i = (b - 384) * 256 + t;
    out2[i] = (float)mask[i];
  }
}

// ------- GroupNorm apply + transpose -> bf16 [n, l, c] -------
__global__ __launch_bounds__(256) void gn_apply_kernel(const float* __restrict__ x,
                                                       const float* __restrict__ w,
                                                       const float* __restrict__ b,
                                                       const float* __restrict__ part,
                                                       unsigned short* __restrict__ xn16) {
  const int l0 = blockIdx.x * 32, c0 = blockIdx.y * 32, n = blockIdx.z;
  const int g16 = n * 8 + (c0 >> 5);
  float s = 0.f, ss = 0.f;
#pragma unroll
  for (int i = 0; i < 8; i++) {
    s  += part[(g16 * 8 + i) * 2 + 0];
    ss += part[(g16 * 8 + i) * 2 + 1];
  }
  const float inv_cnt = 1.0f / (float)(CPG * LLEN);
  const float mu = s * inv_cnt;
  const float rsg = rsqrtf(ss * inv_cnt - mu * mu + GEPS);
  __shared__ float tile[32][33];
  const int tx = threadIdx.x & 31, ty = threadIdx.x >> 5;
#pragma unroll
  for (int i = 0; i < 4; i++) {
    const int c = c0 + ty + 8 * i;
    const float wc = w[c], bc = b[c];
    const float v = x[((size_t)n * CCH + c) * LLEN + l0 + tx];
    tile[ty + 8 * i][tx] = (v - mu) * rsg * wc + bc;
  }
  __syncthreads();
#pragma unroll
  for (int i = 0; i < 4; i++) {
    const int l = l0 + ty + 8 * i;
    xn16[((size_t)n * LLEN + l) * CCH + c0 + tx] = f2b(tile[tx][ty + 8 * i]);
  }
}

// ------- QKV GEMM, bf16 MFMA; outputs in MFMA-fragment-tiled layouts:
//   Q'/K'[n][h][t16(256)][ks(2)]{frag: lane*8+j}   (A/B frag over 16 keys/rows x 64ch)
//   V'[n][h][kc32(128)][ct(4)]{frag: lane*8+j}     (B frag: 16ch x 32 keys)
//   Block = 64 rows x 64 couts, K=256 in LDS, one barrier. -------
__global__ __launch_bounds__(256, 2) void qkv_mfma_kernel(
    const unsigned short* __restrict__ xn16,
    const unsigned short* __restrict__ w16,    // [3][256][256]
    const float* __restrict__ bias_ws,         // [3][256]
    unsigned short* __restrict__ q16,
    unsigned short* __restrict__ k16,
    unsigned short* __restrict__ v16) {
  __shared__ __align__(16) unsigned short aS[64][RS];
  __shared__ __align__(16) unsigned short wS[64][RS];
  const int t = threadIdx.x;
  const int lane = t & 63, wv = t >> 6;
  const int col = lane & 15, quad = lane >> 4;
  const int m0 = blockIdx.x * 64;            // flat (n*L + l) row base
  const int co0 = blockIdx.y * 64;
  const int wsel = blockIdx.z;

  {
    const int r = t >> 2, cu = (t & 3) * 64;
    const unsigned short* srcA = xn16 + (size_t)(m0 + r) * CCH + cu;
    const unsigned short* srcW = w16 + (size_t)wsel * (CCH * CCH) + (size_t)(co0 + r) * CCH + cu;
#pragma unroll
    for (int i = 0; i < 8; i++)
      *(uint4*)&aS[r][cu + i * 8] = *(const uint4*)(srcA + i * 8);
#pragma unroll
    for (int i = 0; i < 8; i++)
      *(uint4*)&wS[r][cu + i * 8] = *(const uint4*)(srcW + i * 8);
  }
  __syncthreads();

  f32x4 acc[4];
#pragma unroll
  for (int i = 0; i < 4; i++) acc[i] = {0.f, 0.f, 0.f, 0.f};

  const int n = m0 >> 12;
  const int h = co0 >> 6;
  const size_t nh = (size_t)(n * NHEAD + h);

  if (wsel < 2) {
    // q/k: D[row][cout]
#pragma unroll
    for (int kc = 0; kc < 8; kc++) {
      const bf16x8 bw = *(const bf16x8*)&wS[wv * 16 + col][kc * 32 + quad * 8];
#pragma unroll
      for (int mt = 0; mt < 4; mt++) {
        const bf16x8 ax = *(const bf16x8*)&aS[mt * 16 + col][kc * 32 + quad * 8];
        acc[mt] = __builtin_amdgcn_mfma_f32_16x16x32_bf16(ax, bw, acc[mt], 0, 0, 0);
      }
    }
    unsigned short* dst = (wsel == 0) ? q16 : k16;
    const float bias = bias_ws[wsel * CCH + co0 + wv * 16 + col];
    // tiled store: ch = wv*16+col -> ks, quadp, j; row -> t16, colp
    const int ks = wv >> 1;
    const int quadp = ((wv & 1) << 1) + (col >> 3);
    const int j = col & 7;
    const int t16b = (m0 & 4095) >> 4;
#pragma unroll
    for (int mt = 0; mt < 4; mt++) {
      const size_t base = ((nh * 256 + (size_t)(t16b + mt)) * 2 + ks) * 512 + quadp * 128 + j;
#pragma unroll
      for (int r = 0; r < 4; r++)
        dst[base + (quad * 4 + r) * 8] = f2b(acc[mt][r] + bias);
    }
  } else {
    // v: D[cout][l]
#pragma unroll
    for (int kc = 0; kc < 8; kc++) {
      const bf16x8 aw = *(const bf16x8*)&wS[wv * 16 + col][kc * 32 + quad * 8];
#pragma unroll
      for (int ct = 0; ct < 4; ct++) {
        const bf16x8 bx = *(const bf16x8*)&aS[ct * 16 + col][kc * 32 + quad * 8];
        acc[ct] = __builtin_amdgcn_mfma_f32_16x16x32_bf16(aw, bx, acc[ct], 0, 0, 0);
      }
    }
    const int kc32b = (m0 & 4095) >> 5;
    const int j = col & 7;
#pragma unroll
    for (int ct = 0; ct < 4; ct++) {
      const int kc32 = kc32b + (ct >> 1);
      const int quadpp = ((ct & 1) << 1) + (col >> 3);
      const size_t base = ((nh * 128 + (size_t)kc32) * 4 + wv) * 512 + quadpp * 128 + j;
#pragma unroll
      for (int r = 0; r < 4; r++) {
        const float bias = bias_ws[2 * CCH + co0 + wv * 16 + quad * 4 + r];
        v16[base + (quad * 4 + r) * 8] = f2b(acc[ct][r] + bias);
      }
    }
  }
}

// ------- Flash attention v3: waves split keys (256 each), no K/V LDS, no loop
//         barriers. Q/K/V read as coalesced fragment-tiled global loads.
//         pT (wave-private) in LDS; O/l merged across waves at block end. -------
__global__ __launch_bounds__(256, 3) void attn_mfma_kernel(
    const unsigned short* __restrict__ q16,   // Q' tiled, pre-scaled
    const unsigned short* __restrict__ k16,   // K' tiled
    const unsigned short* __restrict__ v16,   // V' tiled
    unsigned short* __restrict__ opA,         // bf16 parts 0,1 (each [n,l,c])
    unsigned short* __restrict__ opB,         // bf16 parts 2,3
    float* __restrict__ lpart) {              // [part][n][h][l]
  __shared__ __align__(16) unsigned char shraw[20480];
  unsigned short (*pT)[64][40] = (unsigned short (*)[64][40])shraw;      // [wv][qrow][key32+pad]
  f32x4 (*red)[4][64] = (f32x4 (*)[4][64])shraw;                         // [srcwv][ct][lane]
  f32x4 (*lred)[64] = (f32x4 (*)[64])(shraw + 16384);                    // [srcwv][lane]
  const int t = threadIdx.x;
  const int lane = t & 63, wv = t >> 6;
  const int col = lane & 15, quad = lane >> 4;
  const int q0 = blockIdx.x * 64;
  const int n = blockIdx.y >> 2, h = blockIdx.y & 3;
  const int part = blockIdx.z;
  const int hc = h * HD;
  const size_t baseNL = (size_t)n * LLEN;
  const size_t nh = (size_t)(n * NHEAD + h);
  const unsigned short* kb = k16 + nh * 262144;  // 256*2*512
  const unsigned short* vb = v16 + nh * 262144;  // 128*4*512
  const unsigned short* qb = q16 + nh * 262144;

  // Q B-frags for the block's 64 rows (shared by all waves)
  bf16x8 bq[4][2];
#pragma unroll
  for (int qt = 0; qt < 4; qt++)
#pragma unroll
    for (int ks = 0; ks < 2; ks++)
      bq[qt][ks] = *(const bf16x8*)(qb + (((size_t)((q0 >> 4) + qt) * 2 + ks) * 512) + lane * 8);

  bf16x8 bones;
#pragma unroll
  for (int i = 0; i < 8; i++) bones[i] = (short)0x3F80;   // bf16 1.0

  f32x4 o[4][4], lacc[4];
#pragma unroll
  for (int qt = 0; qt < 4; qt++) {
    lacc[qt] = {0.f, 0.f, 0.f, 0.f};
#pragma unroll
    for (int ct = 0; ct < 4; ct++) o[qt][ct] = {0.f, 0.f, 0.f, 0.f};
  }

  const int kbase = part * 1024 + wv * 256;    // this wave's private key slice
  for (int chunk = 0; chunk < 8; chunk++) {
    const int kc = kbase + chunk * 32;
    // V frags first (K=32 over this chunk's keys), coalesced
    bf16x8 bv[4];
#pragma unroll
    for (int ct = 0; ct < 4; ct++)
      bv[ct] = *(const bf16x8*)(vb + (((size_t)(kc >> 5) * 4 + ct) * 512) + lane * 8);
    // K frags (2 x 16-key tiles, 2 ks each)
    bf16x8 ka[2][2];
#pragma unroll
    for (int kt = 0; kt < 2; kt++)
#pragma unroll
      for (int ks = 0; ks < 2; ks++)
        ka[kt][ks] = *(const bf16x8*)(kb + (((size_t)((kc >> 4) + kt) * 2 + ks) * 512) + lane * 8);

    // S^T = K·Q^T per (keytile, qtile); p = 2^s; pack to wave-private pT
#pragma unroll
    for (int kt = 0; kt < 2; kt++)
#pragma unroll
      for (int qt = 0; qt < 4; qt++) {
        f32x4 s = {0.f, 0.f, 0.f, 0.f};
        s = __builtin_amdgcn_mfma_f32_16x16x32_bf16(ka[kt][0], bq[qt][0], s, 0, 0, 0);
        s = __builtin_amdgcn_mfma_f32_16x16x32_bf16(ka[kt][1], bq[qt][1], s, 0, 0, 0);
        uint2 w;
        w.x = pack2bf(exp2_(s[0]), exp2_(s[1]));
        w.y = pack2bf(exp2_(s[2]), exp2_(s[3]));
        *(uint2*)&pT[wv][qt * 16 + col][kt * 16 + quad * 4] = w;
      }
    // PV: pa = P A-frag (K=32); l via ones-MFMA
#pragma unroll
    for (int qt = 0; qt < 4; qt++) {
      const bf16x8 pa = *(const bf16x8*)&pT[wv][qt * 16 + col][quad * 8];
      lacc[qt] = __builtin_amdgcn_mfma_f32_16x16x32_bf16(pa, bones, lacc[qt], 0, 0, 0);
#pragma unroll
      for (int ct = 0; ct < 4; ct++)
        o[qt][ct] = __builtin_amdgcn_mfma_f32_16x16x32_bf16(pa, bv[ct], o[qt][ct], 0, 0, 0);
    }
  }

  // ---- merge O and l across the 4 waves (each summed a disjoint key slice) ----
  const size_t TS = (size_t)NBATCH * LLEN * CCH;
  unsigned short* op = (part < 2) ? (opA + (size_t)part * TS) : (opB + (size_t)(part - 2) * TS);
  const size_t lbase = ((size_t)(part * NBATCH + n) * NHEAD + h) * LLEN;
#pragma unroll
  for (int qt = 0; qt < 4; qt++) {
    __syncthreads();
#pragma unroll
    for (int ct = 0; ct < 4; ct++) red[wv][ct][lane] = o[qt][ct];
    lred[wv][lane] = lacc[qt];
    __syncthreads();
    f32x4 os = red[0][wv][lane];
    os += red[1][wv][lane];
    os += red[2][wv][lane];
    os += red[3][wv][lane];
    f32x4 ls = lred[0][lane];
    ls += lred[1][lane];
    ls += lred[2][lane];
    ls += lred[3][lane];
    // wave wv writes ch-tile ct == wv for these 16 rows
#pragma unroll
    for (int r = 0; r < 4; r++)
      op[(baseNL + q0 + qt * 16 + quad * 4 + r) * CCH + hc + wv * 16 + col] = f2b(os[r]);
    if (wv == 0 && col == 0) {
#pragma unroll
      for (int r = 0; r < 4; r++)
        lpart[lbase + q0 + qt * 16 + quad * 4 + r] = ls[r];
    }
  }
}

// ------- Proj GEMM: block = 64 rows x 64 couts, K=256 in LDS. A-staging fuses
//         split-K combine + 1/l normalize. One barrier. -------
__global__ __launch_bounds__(256, 2) void proj_mfma_kernel(
    const unsigned short* __restrict__ opA,     // bf16 parts 0,1
    const unsigned short* __restrict__ opB,     // bf16 parts 2,3
    const float* __restrict__ lpart,            // [part][n][h][l]
    const unsigned short* __restrict__ pw16,    // [256][256] bf16
    const float* __restrict__ pbias,            // [256]
    const float* __restrict__ x,
    float* __restrict__ out) {
  __shared__ __align__(16) unsigned short aS[64][RS];
  __shared__ __align__(16) unsigned short wS[64][RS];
  const size_t TS = (size_t)NBATCH * LLEN * CCH;
  const size_t LPS = (size_t)NBATCH * NHEAD * LLEN;
  const int t = threadIdx.x;
  const int lane = t & 63, wv = t >> 6;
  const int col = lane & 15, quad = lane >> 4;
  const int m0 = blockIdx.x * 64;
  const int co0 = blockIdx.y * 64;
  const int n = m0 >> 12, l0 = m0 & 4095;

  {
    const int r = t >> 2, cu = (t & 3) * 64;   // cu/64 = head for this chunk
    const unsigned short* srcW = pw16 + (size_t)(co0 + r) * CCH + cu;
#pragma unroll
    for (int i = 0; i < 8; i++)
      *(uint4*)&wS[r][cu + i * 8] = *(const uint4*)(srcW + i * 8);
    const int l = l0 + r;
    const int h = t & 3;
    float ls = 0.f;
#pragma unroll
    for (int p = 0; p < 4; p++)
      ls += lpart[p * LPS + ((size_t)n * NHEAD + h) * LLEN + l];
    const float linv = 1.0f / ls;
    const size_t e0 = (size_t)(m0 + r) * CCH + cu;
#pragma unroll
    for (int i = 0; i < 8; i++) {
      const size_t e = e0 + (size_t)i * 8;
      const uint4 u0 = *(const uint4*)(opA + e);
      const uint4 u1 = *(const uint4*)(opA + TS + e);
      const uint4 u2 = *(const uint4*)(opB + e);
      const uint4 u3 = *(const uint4*)(opB + TS + e);
      uint4 res;
#pragma unroll
      for (int j = 0; j < 4; j++) {
        const unsigned a = (&u0.x)[j], bb = (&u1.x)[j], cc = (&u2.x)[j], dd = (&u3.x)[j];
        const float lo = (b2f((unsigned short)a) + b2f((unsigned short)bb) +
                          b2f((unsigned short)cc) + b2f((unsigned short)dd)) * linv;
        const float hi = (b2f((unsigned short)(a >> 16)) + b2f((unsigned short)(bb >> 16)) +
                          b2f((unsigned short)(cc >> 16)) + b2f((unsigned short)(dd >> 16))) * linv;
        (&res.x)[j] = pack2bf(lo, hi);
      }
      *(uint4*)&aS[r][cu + i * 8] = res;
    }
  }
  __syncthreads();

  f32x4 acc[4];
#pragma unroll
  for (int i = 0; i < 4; i++) acc[i] = {0.f, 0.f, 0.f, 0.f};
#pragma unroll
  for (int kc = 0; kc < 8; kc++) {
    const bf16x8 aw = *(const bf16x8*)&wS[wv * 16 + col][kc * 32 + quad * 8];
#pragma unroll
    for (int ct = 0; ct < 4; ct++) {
      const bf16x8 ba = *(const bf16x8*)&aS[ct * 16 + col][kc * 32 + quad * 8];
      acc[ct] = __builtin_amdgcn_mfma_f32_16x16x32_bf16(aw, ba, acc[ct], 0, 0, 0);
    }
  }
#pragma unroll
  for (int ct = 0; ct < 4; ct++)
#pragma unroll
    for (int r = 0; r < 4; r++) {
      const int cout = co0 + wv * 16 + quad * 4 + r;
      const size_t idx = ((size_t)(n * CCH + cout)) * LLEN + l0 + ct * 16 + col;
      out[idx] = acc[ct][r] + pbias[cout] + x[idx];
    }
}

extern "C" void kernel_launch(void* const* d_in, const int* in_sizes, int n_in,
                              void* d_out, int out_size, void* d_ws, size_t ws_size,
                              hipStream_t stream) {
  (void)in_sizes; (void)n_in; (void)out_size; (void)ws_size;
  const float* x      = (const float*)d_in[0];
  const int*   mask   = (const int*)d_in[1];
  const float* norm_w = (const float*)d_in[2];
  const float* norm_b = (const float*)d_in[3];
  const float* q_w    = (const float*)d_in[4];
  const float* q_b    = (const float*)d_in[5];
  const float* k_w    = (const float*)d_in[6];
  const float* k_b    = (const float*)d_in[7];
  const float* v_w    = (const float*)d_in[8];
  const float* v_b    = (const float*)d_in[9];
  const float* p_w    = (const float*)d_in[10];
  const float* p_b    = (const float*)d_in[11];

  const size_t TSZ = (size_t)NBATCH * LLEN * CCH;   // 2097152 elements
  unsigned short* xn16 = (unsigned short*)d_ws;     // TSZ
  unsigned short* q16  = xn16 + TSZ;                // tiled
  unsigned short* k16  = q16 + TSZ;                 // tiled
  unsigned short* v16  = k16 + TSZ;                 // tiled
  unsigned short* opA  = v16 + TSZ;                 // 2*TSZ
  unsigned short* opB  = opA + 2 * TSZ;             // 2*TSZ
  unsigned short* w16  = opB + 2 * TSZ;             // 4*65536
  float* bias_ws = (float*)(w16 + 4 * 65536);       // 4*256
  float* lpart   = bias_ws + 1024;                  // KSPLIT*N*H*L
  float* part    = lpart + (size_t)KSPLIT * NBATCH * NHEAD * LLEN;  // 256

  float* out  = (float*)d_out;
  float* out2 = out + TSZ;   // mask chunk

  setup_kernel<<<416, 256, 0, stream>>>(q_w, k_w, v_w, p_w, q_b, k_b, v_b, p_b,
                                        x, mask, w16, bias_ws, part, out2);
  gn_apply_kernel<<<dim3(LLEN / 32, CCH / 32, NBATCH), 256, 0, stream>>>(
      x, norm_w, norm_b, part, xn16);
  qkv_mfma_kernel<<<dim3((NBATCH * LLEN) / 64, CCH / 64, 3), 256, 0, stream>>>(
      xn16, w16, bias_ws, q16, k16, v16);
  attn_mfma_kernel<<<dim3(LLEN / 64, NBATCH * NHEAD, KSPLIT), 256, 0, stream>>>(
      q16, k16, v16, opA, opB, lpart);
  proj_mfma_kernel<<<dim3((NBATCH * LLEN) / 64, CCH / 64), 256, 0, stream>>>(
      opA, opB, lpart, w16 + 3 * 65536, bias_ws + 768, x, out);
}

// Round 11
// 154.188 us; speedup vs baseline: 1.0887x; 1.0887x over previous
//
#include <hip/hip_runtime.h>
#include <hip/hip_bf16.h>

// Problem constants (N=2, C=256, H=W=64) — float32 I/O per reference.
#define NBATCH 2
#define CCH    256
#define LLEN   4096      // H*W
#define NGROUP 8
#define CPG    32        // C / NGROUP
#define NHEAD  4
#define HD     64        // C / NHEAD
#define GEPS   1e-5f
// q pre-scale: hd^-0.5 * log2(e); scores feed v_exp_f32 (2^x) directly.
#define QSCALE 0.18033688011112042f

// Generic MFMA fragment tiling (for 16x16x32 bf16): a [R x 256ch] tensor is
// stored as tiles [r16][c32] of 512 ushorts; element (r, c) sits at
// tile*512 + ((r&15) + 16*((c>>3)&3))*8 + (c&7).  The same frag serves as
// A-operand (lane col = r, k = ch) and B-operand (lane col = r, k = ch).

typedef short bf16x8 __attribute__((ext_vector_type(8)));
typedef float f32x4  __attribute__((ext_vector_type(4)));

__device__ __forceinline__ unsigned short f2b(float f) {
  unsigned u = __float_as_uint(f);
  u += 0x7FFFu + ((u >> 16) & 1u);
  return (unsigned short)(u >> 16);
}
__device__ __forceinline__ unsigned pack2bf(float a, float b) {
  __hip_bfloat162 h = __float22bfloat162_rn(make_float2(a, b));
  union { __hip_bfloat162 h; unsigned u; } c;
  c.h = h;
  return c.u;
}
__device__ __forceinline__ float exp2_(float x) {
#if __has_builtin(__builtin_amdgcn_exp2f)
  return __builtin_amdgcn_exp2f(x);
#else
  return exp2f(x);
#endif
}

// ------- setup: wcvt->tiled W (blocks 0..255) | gn partials (256..383) | mask (384..415) -------
__global__ __launch_bounds__(256) void setup_kernel(
    const float* __restrict__ qw, const float* __restrict__ kw,
    const float* __restrict__ vw, const float* __restrict__ pw,
    const float* __restrict__ qb, const float* __restrict__ kb,
    const float* __restrict__ vb, const float* __restrict__ pb,
    const float* __restrict__ x, const int* __restrict__ mask,
    unsigned short* __restrict__ w16, float* __restrict__ bias_ws,
    float* __restrict__ part, float* __restrict__ out2) {
  __shared__ float rs[4], rss[4];
  const int b = blockIdx.x;
  const int t = threadIdx.x;
  if (b < 256) {
    const int idx = b * 256 + t;               // float4 units; 65536 total
    const int m = idx >> 14;
    const int rem = idx & 16383;
    const int cout = rem >> 6;                 // 0..255
    const int ch4 = (rem & 63) << 2;           // 0..252
    const float* src[4] = {qw, kw, vw, pw};
    const float sc = (m == 0) ? QSCALE : 1.0f;
    const float4 v = ((const float4*)src[m])[(size_t)cout * 64 + (ch4 >> 2)];
    // tiled store: [(m*16 + cout>>4)*8 + ch>>5]*512 + lane'*8 + ch&7
    unsigned short* dst = w16 +
        ((size_t)(m * 16 + (cout >> 4)) * 8 + (ch4 >> 5)) * 512 +
        ((cout & 15) + 16 * ((ch4 >> 3) & 3)) * 8 + (ch4 & 7);
    dst[0] = f2b(v.x * sc); dst[1] = f2b(v.y * sc);
    dst[2] = f2b(v.z * sc); dst[3] = f2b(v.w * sc);
    if (b == 0) {
      bias_ws[t]       = qb[t] * QSCALE;
      bias_ws[256 + t] = kb[t];
      bias_ws[512 + t] = vb[t];
      bias_ws[768 + t] = pb[t];
    }
  } else if (b < 384) {
    const int sb = b - 256;
    const int gidx = sb >> 3, sub = sb & 7;
    const float4* xp = (const float4*)(x + (size_t)gidx * (CPG * LLEN)) + (size_t)sub * 4096;
    float s = 0.f, ss = 0.f;
    for (int i = t; i < 4096; i += 256) {
      const float4 v = xp[i];
      s += v.x + v.y + v.z + v.w;
      ss = fmaf(v.x, v.x, ss);
      ss = fmaf(v.y, v.y, ss);
      ss = fmaf(v.z, v.z, ss);
      ss = fmaf(v.w, v.w, ss);
    }
#pragma unroll
    for (int off = 32; off; off >>= 1) {
      s  += __shfl_down(s, off);
      ss += __shfl_down(ss, off);
    }
    if ((t & 63) == 0) { rs[t >> 6] = s; rss[t >> 6] = ss; }
    __syncthreads();
    if (t == 0) {
      part[sb * 2 + 0] = rs[0] + rs[1] + rs[2] + rs[3];
      part[sb * 2 + 1] = rss[0] + rss[1] + rss[2] + rss[3];
    }
  } else {
    const int i = (b - 384) * 256 + t;
    out2[i] = (float)mask[i];
  }
}

// ------- GroupNorm apply + transpose -> bf16 xn, fragment-tiled [n][l16 256][c32 8][512] -------
__global__ __launch_bounds__(256) void gn_apply_kernel(const float* __restrict__ x,
                                                       const float* __restrict__ w,
                                                       const float* __restrict__ b,
                                                       const float* __restrict__ part,
                                                       unsigned short* __restrict__ xn16) {
  const int l0 = blockIdx.x * 32, c0 = blockIdx.y * 32, n = blockIdx.z;
  const int g16 = n * 8 + (c0 >> 5);
  float s = 0.f, ss = 0.f;
#pragma unroll
  for (int i = 0; i < 8; i++) {
    s  += part[(g16 * 8 + i) * 2 + 0];
    ss += part[(g16 * 8 + i) * 2 + 1];
  }
  const float inv_cnt = 1.0f / (float)(CPG * LLEN);
  const float mu = s * inv_cnt;
  const float rsg = rsqrtf(ss * inv_cnt - mu * mu + GEPS);
  __shared__ float tile[32][33];
  const int tx = threadIdx.x & 31, ty = threadIdx.x >> 5;
#pragma unroll
  for (int i = 0; i < 4; i++) {
    const int c = c0 + ty + 8 * i;
    const float wc = w[c], bc = b[c];
    const float v = x[((size_t)n * CCH + c) * LLEN + l0 + tx];
    tile[ty + 8 * i][tx] = (v - mu) * rsg * wc + bc;
  }
  __syncthreads();
  const int c = c0 + tx;
#pragma unroll
  for (int i = 0; i < 4; i++) {
    const int l = l0 + ty + 8 * i;
    const size_t pos = (((size_t)n * 256 + (l >> 4)) * 8 + (c >> 5)) * 512 +
                       ((l & 15) + 16 * ((c >> 3) & 3)) * 8 + (c & 7);
    xn16[pos] = f2b(tile[tx][ty + 8 * i]);
  }
}

// ------- QKV GEMM, LDS-free register MFMA. Block = 64 rows x 64 couts.
//   All frags are direct coalesced loads from tiled xn / tiled W.
//   q/k stored row-tiled (Q'/K' for attn); v stored key x ch tiled (V'). -------
__global__ __launch_bounds__(256, 4) void qkv_mfma_kernel(
    const unsigned short* __restrict__ xn16,
    const unsigned short* __restrict__ w16,
    const float* __restrict__ bias_ws,
    unsigned short* __restrict__ q16,
    unsigned short* __restrict__ k16,
    unsigned short* __restrict__ v16) {
  const int t = threadIdx.x;
  const int lane = t & 63, wv = t >> 6;
  const int col = lane & 15, quad = lane >> 4;
  const int m0 = blockIdx.x * 64;
  const int by = blockIdx.y;                 // cout block (64)
  const int co0 = by * 64;
  const int wsel = blockIdx.z;
  const int n = m0 >> 12;
  const int m16b = (m0 & 4095) >> 4;

  const unsigned short* xnb = xn16 + (size_t)n * (256 * 8 * 512);
  const unsigned short* wb  = w16 + ((size_t)(wsel * 16 + by * 4 + wv) * 8) * 512 + lane * 8;

  f32x4 acc[4];
#pragma unroll
  for (int i = 0; i < 4; i++) acc[i] = {0.f, 0.f, 0.f, 0.f};

#pragma unroll
  for (int kc = 0; kc < 8; kc++) {
    const bf16x8 wf = *(const bf16x8*)(wb + (size_t)kc * 512);
#pragma unroll
    for (int mt = 0; mt < 4; mt++) {
      const bf16x8 xf = *(const bf16x8*)(xnb + ((size_t)(m16b + mt) * 8 + kc) * 512 + lane * 8);
      acc[mt] = (wsel < 2)
          ? __builtin_amdgcn_mfma_f32_16x16x32_bf16(xf, wf, acc[mt], 0, 0, 0)   // D[row][cout]
          : __builtin_amdgcn_mfma_f32_16x16x32_bf16(wf, xf, acc[mt], 0, 0, 0);  // D[cout][l]
    }
  }

  if (wsel < 2) {
    unsigned short* dst = (wsel == 0) ? q16 : k16;
    const float bias = bias_ws[wsel * CCH + co0 + wv * 16 + col];
    const int lquad = (wv * 2 + (col >> 3)) & 3;
    const int j = col & 7;
#pragma unroll
    for (int mt = 0; mt < 4; mt++) {
      const size_t base = ((size_t)(n * 256 + m16b + mt) * 8 + by * 2 + (wv >> 1)) * 512 + j;
#pragma unroll
      for (int r = 0; r < 4; r++)
        dst[base + ((quad * 4 + r) + 16 * lquad) * 8] = f2b(acc[mt][r] + bias);
    }
  } else {
    const int l0 = m0 & 4095;
    const int j = col & 7;
#pragma unroll
    for (int ct = 0; ct < 4; ct++) {
      const size_t base = ((size_t)(n * 128 + (l0 >> 5) + (ct >> 1)) * 16 + by * 4 + wv) * 512 +
                          16 * (((ct & 1) << 1) + (col >> 3)) * 8 + j;
#pragma unroll
      for (int r = 0; r < 4; r++) {
        const int cout = co0 + wv * 16 + quad * 4 + r;
        v16[base + (quad * 4 + r) * 8] = f2b(acc[ct][r] + bias_ws[2 * CCH + cout]);
      }
    }
  }
}

// ------- Flash attention v4: KSPLIT=1, waves own 1024-key slices, register
//   prefetch, no K/V LDS, in-kernel normalize, O stored fragment-tiled. -------
__global__ __launch_bounds__(256, 2) void attn_mfma_kernel(
    const unsigned short* __restrict__ q16,   // Q' tiled, pre-scaled
    const unsigned short* __restrict__ k16,   // K' tiled
    const unsigned short* __restrict__ v16,   // V' tiled
    unsigned short* __restrict__ o16) {       // O' tiled (normalized)
  __shared__ __align__(16) unsigned char shraw[20480];
  unsigned short (*pT)[64][40] = (unsigned short (*)[64][40])shraw;   // [wv][qrow][key+pad]
  f32x4 (*red)[4][64] = (f32x4 (*)[4][64])shraw;                      // [srcwv][ct][lane]
  f32x4 (*lred)[64] = (f32x4 (*)[64])(shraw + 16384);                 // [srcwv][lane]
  const int t = threadIdx.x;
  const int lane = t & 63, wv = t >> 6;
  const int col = lane & 15, quad = lane >> 4;
  const int q0 = blockIdx.x * 64;
  const int n = blockIdx.y >> 2, h = blockIdx.y & 3;
  const int hc = h * HD;

  const unsigned short* qb = q16 + (size_t)n * (256 * 8 * 512);
  const unsigned short* kb = k16 + (size_t)n * (256 * 8 * 512);
  const unsigned short* vb = v16 + (size_t)n * (128 * 16 * 512);

  // Q B-frags (shared by all waves)
  bf16x8 bq[4][2];
#pragma unroll
  for (int qt = 0; qt < 4; qt++)
#pragma unroll
    for (int ks = 0; ks < 2; ks++)
      bq[qt][ks] = *(const bf16x8*)(qb + ((size_t)(blockIdx.x * 4 + qt) * 8 + h * 2 + ks) * 512 + lane * 8);

  bf16x8 bones;
#pragma unroll
  for (int i = 0; i < 8; i++) bones[i] = (short)0x3F80;   // bf16 1.0

  f32x4 o[4][4], lacc[4];
#pragma unroll
  for (int qt = 0; qt < 4; qt++) {
    lacc[qt] = {0.f, 0.f, 0.f, 0.f};
#pragma unroll
    for (int ct = 0; ct < 4; ct++) o[qt][ct] = {0.f, 0.f, 0.f, 0.f};
  }

  auto ldK = [&](int kc0, int kt, int ks) {
    return *(const bf16x8*)(kb + ((size_t)((kc0 >> 4) + kt) * 8 + h * 2 + ks) * 512 + lane * 8);
  };
  auto ldV = [&](int kc0, int ct) {
    return *(const bf16x8*)(vb + ((size_t)(kc0 >> 5) * 16 + h * 4 + ct) * 512 + lane * 8);
  };

  int kc0 = wv * 1024;                       // this wave's private key slice
  bf16x8 ka[2][2], bv[4];
#pragma unroll
  for (int kt = 0; kt < 2; kt++)
#pragma unroll
    for (int ks = 0; ks < 2; ks++) ka[kt][ks] = ldK(kc0, kt, ks);
#pragma unroll
  for (int ct = 0; ct < 4; ct++) bv[ct] = ldV(kc0, ct);

  for (int chunk = 0; chunk < 32; chunk++) {
    const int kn = (chunk < 31) ? kc0 + 32 : kc0;
    bf16x8 nka[2][2], nbv[4];
#pragma unroll
    for (int kt = 0; kt < 2; kt++)
#pragma unroll
      for (int ks = 0; ks < 2; ks++) nka[kt][ks] = ldK(kn, kt, ks);
#pragma unroll
    for (int ct = 0; ct < 4; ct++) nbv[ct] = ldV(kn, ct);

    // S^T = K·Q^T; p = 2^s; pack to wave-private pT
#pragma unroll
    for (int kt = 0; kt < 2; kt++)
#pragma unroll
      for (int qt = 0; qt < 4; qt++) {
        f32x4 s = {0.f, 0.f, 0.f, 0.f};
        s = __builtin_amdgcn_mfma_f32_16x16x32_bf16(ka[kt][0], bq[qt][0], s, 0, 0, 0);
        s = __builtin_amdgcn_mfma_f32_16x16x32_bf16(ka[kt][1], bq[qt][1], s, 0, 0, 0);
        uint2 w;
        w.x = pack2bf(exp2_(s[0]), exp2_(s[1]));
        w.y = pack2bf(exp2_(s[2]), exp2_(s[3]));
        *(uint2*)&pT[wv][qt * 16 + col][kt * 16 + quad * 4] = w;
      }
    // PV + denominators
#pragma unroll
    for (int qt = 0; qt < 4; qt++) {
      const bf16x8 pa = *(const bf16x8*)&pT[wv][qt * 16 + col][quad * 8];
      lacc[qt] = __builtin_amdgcn_mfma_f32_16x16x32_bf16(pa, bones, lacc[qt], 0, 0, 0);
#pragma unroll
      for (int ct = 0; ct < 4; ct++)
        o[qt][ct] = __builtin_amdgcn_mfma_f32_16x16x32_bf16(pa, bv[ct], o[qt][ct], 0, 0, 0);
    }
#pragma unroll
    for (int kt = 0; kt < 2; kt++)
#pragma unroll
      for (int ks = 0; ks < 2; ks++) ka[kt][ks] = nka[kt][ks];
#pragma unroll
    for (int ct = 0; ct < 4; ct++) bv[ct] = nbv[ct];
    kc0 = kn;
  }

  // ---- merge across 4 waves, normalize, store O' tiled ----
  const int cch = hc + wv * 16 + col;        // channel this thread stores
  const int lquad16 = 16 * ((cch >> 3) & 3);
  const size_t ctile = cch >> 5;
#pragma unroll
  for (int qt = 0; qt < 4; qt++) {
    __syncthreads();
#pragma unroll
    for (int ct = 0; ct < 4; ct++) red[wv][ct][lane] = o[qt][ct];
    lred[wv][lane] = lacc[qt];
    __syncthreads();
    f32x4 os = red[0][wv][lane];
    os += red[1][wv][lane];
    os += red[2][wv][lane];
    os += red[3][wv][lane];
    f32x4 ls = lred[0][lane];
    ls += lred[1][lane];
    ls += lred[2][lane];
    ls += lred[3][lane];
    const size_t base = (((size_t)n * 256 + blockIdx.x * 4 + qt) * 8 + ctile) * 512 + (cch & 7);
#pragma unroll
    for (int r = 0; r < 4; r++)
      o16[base + ((quad * 4 + r) + lquad16) * 8] = f2b(os[r] / ls[r]);
  }
}

// ------- Proj GEMM, LDS-free register MFMA + bias + residual -> fp32 out [n,c,l] -------
__global__ __launch_bounds__(256, 4) void proj_mfma_kernel(
    const unsigned short* __restrict__ o16,     // O' tiled
    const unsigned short* __restrict__ w16,     // tiled weights (pw at tile 48)
    const float* __restrict__ pbias,
    const float* __restrict__ x,
    float* __restrict__ out) {
  const int t = threadIdx.x;
  const int lane = t & 63, wv = t >> 6;
  const int col = lane & 15, quad = lane >> 4;
  const int m0 = blockIdx.x * 64;            // l rows
  const int by = blockIdx.y;
  const int co0 = by * 64;
  const int n = m0 >> 12, l0 = m0 & 4095;

  const unsigned short* ob = o16 + (size_t)n * (256 * 8 * 512);
  const unsigned short* wb = w16 + ((size_t)(48 + by * 4 + wv) * 8) * 512 + lane * 8;

  f32x4 acc[4];
#pragma unroll
  for (int i = 0; i < 4; i++) acc[i] = {0.f, 0.f, 0.f, 0.f};

#pragma unroll
  for (int kc = 0; kc < 8; kc++) {
    const bf16x8 aw = *(const bf16x8*)(wb + (size_t)kc * 512);
#pragma unroll
    for (int lt = 0; lt < 4; lt++) {
      const bf16x8 bo = *(const bf16x8*)(ob + ((size_t)((l0 >> 4) + lt) * 8 + kc) * 512 + lane * 8);
      acc[lt] = __builtin_amdgcn_mfma_f32_16x16x32_bf16(aw, bo, acc[lt], 0, 0, 0);  // D[cout][l]
    }
  }
#pragma unroll
  for (int lt = 0; lt < 4; lt++)
#pragma unroll
    for (int r = 0; r < 4; r++) {
      const int cout = co0 + wv * 16 + quad * 4 + r;
      const size_t idx = ((size_t)(n * CCH + cout)) * LLEN + l0 + lt * 16 + col;
      out[idx] = acc[lt][r] + pbias[cout] + x[idx];
    }
}

extern "C" void kernel_launch(void* const* d_in, const int* in_sizes, int n_in,
                              void* d_out, int out_size, void* d_ws, size_t ws_size,
                              hipStream_t stream) {
  (void)in_sizes; (void)n_in; (void)out_size; (void)ws_size;
  const float* x      = (const float*)d_in[0];
  const int*   mask   = (const int*)d_in[1];
  const float* norm_w = (const float*)d_in[2];
  const float* norm_b = (const float*)d_in[3];
  const float* q_w    = (const float*)d_in[4];
  const float* q_b    = (const float*)d_in[5];
  const float* k_w    = (const float*)d_in[6];
  const float* k_b    = (const float*)d_in[7];
  const float* v_w    = (const float*)d_in[8];
  const float* v_b    = (const float*)d_in[9];
  const float* p_w    = (const float*)d_in[10];
  const float* p_b    = (const float*)d_in[11];

  const size_t TSZ = (size_t)NBATCH * LLEN * CCH;   // 2097152 elements
  unsigned short* xn16 = (unsigned short*)d_ws;     // TSZ (tiled)
  unsigned short* q16  = xn16 + TSZ;                // tiled
  unsigned short* k16  = q16 + TSZ;                 // tiled
  unsigned short* v16  = k16 + TSZ;                 // tiled
  unsigned short* o16  = v16 + TSZ;                 // tiled
  unsigned short* w16  = o16 + TSZ;                 // 4*65536 (tiled)
  float* bias_ws = (float*)(w16 + 4 * 65536);       // 4*256
  float* part    = bias_ws + 1024;                  // 256
  // total ~21 MB

  float* out  = (float*)d_out;
  float* out2 = out + TSZ;   // mask chunk

  setup_kernel<<<416, 256, 0, stream>>>(q_w, k_w, v_w, p_w, q_b, k_b, v_b, p_b,
                                        x, mask, w16, bias_ws, part, out2);
  gn_apply_kernel<<<dim3(LLEN / 32, CCH / 32, NBATCH), 256, 0, stream>>>(
      x, norm_w, norm_b, part, xn16);
  qkv_mfma_kernel<<<dim3((NBATCH * LLEN) / 64, CCH / 64, 3), 256, 0, stream>>>(
      xn16, w16, bias_ws, q16, k16, v16);
  attn_mfma_kernel<<<dim3(LLEN / 64, NBATCH * NHEAD), 256, 0, stream>>>(
      q16, k16, v16, o16);
  proj_mfma_kernel<<<dim3((NBATCH * LLEN) / 64, CCH / 64), 256, 0, stream>>>(
      o16, w16, bias_ws + 768, x, out);
}